// Round 1
// baseline (178.487 us; speedup 1.0000x reference)
//
#include <hip/hip_runtime.h>

// StructuralLoss: predictions (64, 8192, 60) fp32, rows of 60 floats = 15 float4s.
// Per key base b=20k within a row:
//   bid-viol pairs start at b+{0,2,4,6}:   max(p[i+2]-p[i], 0)
//   ask-viol pairs start at b+{10,12,14,16}: max(p[i]-p[i+2], 0)
//   spread at b: max(p[b]-p[b+10], 0)
// Thread per float4 f (elements 4f..4f+3). Case c = f%5:
//   pair A = (a.x, a.z):                 dA = {+1,+1,0,-1,-1}[c]
//   pair B = (a.z, x of f+1):            dB = {+1,+1,-1,-1,0}[c]
//   spread (a.x, z of f+2):              only c==0
//
// v2 changes vs prior round:
//  - n0/z2 fetched via __shfl_down from lanes +1/+2 (ds_bpermute, LDS pipe)
//    instead of 2 stride-16B global dword gathers per iter. VMEM insts/iter 3->1.
//    Edge lanes (62,63) and buffer tail fall back to predicated global loads
//    (1-2 active lanes/wave, L2-hot).
//  - c=f%5 computed once per thread, updated incrementally (+stride%5 mod 5).
// Launcher invariant: grid=2048, block=256 -> stride=524288, nf4=7864320=15*stride,
// so all lanes of a wave run the same trip count (shfl exec-uniformity).

__global__ __launch_bounds__(256) void sl_partial(
    const float4* __restrict__ p4, const float* __restrict__ p,
    float* __restrict__ partial, unsigned nf4) {
    unsigned tid = threadIdx.x;
    unsigned gid = blockIdx.x * 256u + tid;
    unsigned stride = gridDim.x * 256u;
    unsigned lane = tid & 63u;

    float s = 0.0f;
    unsigned c = gid % 5u;          // one magic-mul, once
    unsigned cinc = stride % 5u;    // 3 for the fixed launch config

    for (unsigned f = gid; f < nf4; f += stride) {
        float4 a = p4[f];

        // neighbor values live in adjacent lanes' registers
        float n0 = __shfl_down(a.x, 1, 64);   // x of f+1
        float z2 = __shfl_down(a.z, 2, 64);   // z of f+2

        // wave-edge / buffer-tail fallback (1-2 active lanes per wave)
        if (lane >= 62u || f + 2u >= nf4) {
            unsigned f2 = f + 2u; if (f2 >= nf4) f2 = nf4 - 1u;
            z2 = p[(size_t)f2 * 4u + 2u];
            if (lane == 63u || f + 1u >= nf4) {
                unsigned fn = f + 1u; if (fn >= nf4) fn = nf4 - 1u;
                n0 = p[(size_t)fn * 4u];
            }
        }

        float dA = (c < 2u) ? 1.0f : ((c == 2u) ? 0.0f : -1.0f);
        float dB = (c < 2u) ? 1.0f : ((c == 4u) ? 0.0f : -1.0f);

        s += fmaxf(dA * (a.z - a.x), 0.0f);
        s += fmaxf(dB * (n0 - a.z), 0.0f);
        s += (c == 0u) ? fmaxf(a.x - z2, 0.0f) : 0.0f;

        c += cinc; if (c >= 5u) c -= 5u;
    }

    // wave (64) shuffle reduce, then 4-wave LDS reduce
#pragma unroll
    for (int off = 32; off > 0; off >>= 1) s += __shfl_down(s, off, 64);
    __shared__ float ws[4];
    if ((threadIdx.x & 63u) == 0u) ws[threadIdx.x >> 6] = s;
    __syncthreads();
    if (threadIdx.x == 0)
        partial[blockIdx.x] = ws[0] + ws[1] + ws[2] + ws[3];
}

__global__ __launch_bounds__(256) void sl_final(
    const float* __restrict__ partial, float* __restrict__ out, int n) {
    float s = 0.0f;
    for (int i = threadIdx.x; i < n; i += 256) s += partial[i];
#pragma unroll
    for (int off = 32; off > 0; off >>= 1) s += __shfl_down(s, off, 64);
    __shared__ float ws[4];
    if ((threadIdx.x & 63u) == 0u) ws[threadIdx.x >> 6] = s;
    __syncthreads();
    if (threadIdx.x == 0)
        out[0] = (ws[0] + ws[1] + ws[2] + ws[3]) * (1.0f / 64.0f);
}

extern "C" void kernel_launch(void* const* d_in, const int* in_sizes, int n_in,
                              void* d_out, int out_size, void* d_ws, size_t ws_size,
                              hipStream_t stream) {
    const float* pred = (const float*)d_in[0];
    float* out = (float*)d_out;
    float* partial = (float*)d_ws;  // 2048 floats, fully overwritten each launch

    unsigned nf4 = (unsigned)(in_sizes[0] / 4);  // 7,864,320
    int grid = 2048;                             // 524288 threads -> exactly 15 f4/thread

    sl_partial<<<grid, 256, 0, stream>>>(
        (const float4*)pred, pred, partial, nf4);
    sl_final<<<1, 256, 0, stream>>>(partial, out, grid);
}